// Round 4
// baseline (265.361 us; speedup 1.0000x reference)
//
#include <hip/hip_runtime.h>
#include <math.h>

#define BDIM 512
#define IDIM 256
#define ODIM 512

// jnp.minimum(q, 1.0): NaN-propagating min with 1.0
__device__ __forceinline__ float np_min1(float q) {
    return (q < 1.0f) ? q : ((q != q) ? q : 1.0f);
}

// np.argmin update rule: strict < (first occurrence wins), NaN-first.
__device__ __forceinline__ bool np_argmin_better(float s, float best) {
    return (s < best) || (isnan(s) && !isnan(best));
}

// Correctly-rounded fp32 divide num/den given a correctly-rounded fp64
// reciprocal r = 1/(double)den, WITHOUT v_div_* (no VCC serialization).
// fp64 Markstein: q64 err <= ~2^-52.5 rel; an inexact quotient of two
// 24-bit significands lies >= 2^-49 from any fp32 rounding boundary, so
// cvt_f32_f64 yields exactly the RN fp32 quotient. den==0 -> IEEE num/0.
__device__ __forceinline__ float div_rn_via_r64(float num, float den, double r) {
    double n   = (double)num;
    double q0  = n * r;
    double rem = fma(-(double)den, q0, n);
    double q   = fma(rem, r, q0);
    float  qf  = (float)q;
    return (den == 0.0f) ? num * (float)INFINITY : qf;
}

// K1: fp64 reciprocals of den = fl(1 - fl(1 - v)) for x and w.
// One hw fp64 divide per thread (no chain -> VCC serialization irrelevant).
__global__ __launch_bounds__(256) void recip_kernel(const float* __restrict__ x,
                                                    const float* __restrict__ w,
                                                    double* __restrict__ rx,
                                                    double* __restrict__ rw) {
    int idx = blockIdx.x * blockDim.x + threadIdx.x;
    const int n = BDIM * IDIM;  // 131072 (== IDIM*ODIM)
    const float* src = (idx < n) ? x : w;
    double*      dst = (idx < n) ? rx : rw;
    int j = (idx < n) ? idx : idx - n;
    float v   = src[j];
    float c   = __fsub_rn(1.0f, v);      // comp
    float den = __fsub_rn(1.0f, c);
    dst[j] = (den == 0.0f) ? (double)INFINITY : 1.0 / (double)den;
}

// K2: rel_x[i,o] = 1 - S/D, sequential-in-b (numpy order).
// Block = i (256): x, rx are wave-uniform -> scalar loads; t coalesced.
__global__ __launch_bounds__(512) void relx_kernel(const float* __restrict__ x,
                                                   const float* __restrict__ t,
                                                   const double* __restrict__ rx,
                                                   float* __restrict__ relx) {
    int o = threadIdx.x;   // 0..511
    int i = blockIdx.x;    // 0..255
    float S = 0.0f, D = 0.0f;
    for (int b = 0; b < BDIM; b += 8) {
        float qm[8], xcs[8];
        #pragma unroll
        for (int u = 0; u < 8; ++u) {
            float  xv = x[(b + u) * IDIM + i];    // uniform -> s_load
            double r  = rx[(b + u) * IDIM + i];   // uniform -> s_load (8B)
            float  tv = t[(b + u) * ODIM + o];    // coalesced
            float xc  = __fsub_rn(1.0f, xv);      // x_comp
            float den = __fsub_rn(1.0f, xc);      // NOT simply xv (rounding!)
            float tc  = __fsub_rn(1.0f, tv);      // t_comp
            float num = __fsub_rn(tc, xc);
            qm[u]  = np_min1(div_rn_via_r64(num, den, r));  // independent
            xcs[u] = xc;
        }
        #pragma unroll
        for (int u = 0; u < 8; ++u) {             // exact sequential order
            S = __fadd_rn(S, qm[u]);
            D = __fadd_rn(D, xcs[u]);
        }
    }
    relx[i * ODIM + o] = __fsub_rn(1.0f, __fdiv_rn(S, D));  // one div/thread
}

// K3: rel_w[b,o] = 1 - S/D, sequential-in-i.
// Block = o (512): w, rw wave-uniform -> scalar loads; tc per-thread (once).
__global__ __launch_bounds__(512) void relw_kernel(const float* __restrict__ w,
                                                   const float* __restrict__ t,
                                                   const double* __restrict__ rw,
                                                   float* __restrict__ relw) {
    int b = threadIdx.x;   // 0..511
    int o = blockIdx.x;    // 0..511
    float tc = __fsub_rn(1.0f, t[b * ODIM + o]);  // strided column, one-time
    float S = 0.0f, D = 0.0f;
    for (int i = 0; i < IDIM; i += 8) {
        float qm[8], wcs[8];
        #pragma unroll
        for (int u = 0; u < 8; ++u) {
            float  wv = w[(i + u) * ODIM + o];    // uniform -> s_load
            double r  = rw[(i + u) * ODIM + o];   // uniform -> s_load
            float wc  = __fsub_rn(1.0f, wv);      // w_comp
            float den = __fsub_rn(1.0f, wc);
            float num = __fsub_rn(tc, wc);
            qm[u]  = np_min1(div_rn_via_r64(num, den, r));
            wcs[u] = wc;
        }
        #pragma unroll
        for (int u = 0; u < 8; ++u) {             // exact sequential order
            S = __fadd_rn(S, qm[u]);
            D = __fadd_rn(D, wcs[u]);
        }
    }
    relw[b * ODIM + o] = __fsub_rn(1.0f, __fdiv_rn(S, D));
}

// K4: both argmins + gathers, fp32 numpy-exact scores. Block = b, thread = o.
__global__ __launch_bounds__(512) void out_kernel(const float* __restrict__ x,
                                                  const float* __restrict__ w,
                                                  const float* __restrict__ relx,
                                                  const float* __restrict__ relw,
                                                  float* __restrict__ out) {
    __shared__ float xrow[IDIM];
    int o = threadIdx.x;   // 0..511
    int b = blockIdx.x;    // 0..511
    if (o < IDIM) xrow[o] = x[b * IDIM + o];
    __syncthreads();

    // ---- ind_w: score = fl(fl(w+rw) - fl(w*rw)) ----
    float rw = relw[b * ODIM + o];                // coalesced row read
    float best; int idx;
    {
        float w0 = w[o];
        best = __fsub_rn(__fadd_rn(w0, rw), __fmul_rn(w0, rw));
        idx = 0;
        int i = 1;
        for (; i + 4 <= IDIM; i += 4) {
            float a0 = w[(i+0) * ODIM + o];
            float a1 = w[(i+1) * ODIM + o];
            float a2 = w[(i+2) * ODIM + o];
            float a3 = w[(i+3) * ODIM + o];
            float s0 = __fsub_rn(__fadd_rn(a0, rw), __fmul_rn(a0, rw));
            float s1 = __fsub_rn(__fadd_rn(a1, rw), __fmul_rn(a1, rw));
            float s2 = __fsub_rn(__fadd_rn(a2, rw), __fmul_rn(a2, rw));
            float s3 = __fsub_rn(__fadd_rn(a3, rw), __fmul_rn(a3, rw));
            if (np_argmin_better(s0, best)) { best = s0; idx = i + 0; }
            if (np_argmin_better(s1, best)) { best = s1; idx = i + 1; }
            if (np_argmin_better(s2, best)) { best = s2; idx = i + 2; }
            if (np_argmin_better(s3, best)) { best = s3; idx = i + 3; }
        }
        for (; i < IDIM; ++i) {
            float a = w[i * ODIM + o];
            float s = __fsub_rn(__fadd_rn(a, rw), __fmul_rn(a, rw));
            if (np_argmin_better(s, best)) { best = s; idx = i; }
        }
    }
    float cw = fmaxf(xrow[idx], w[idx * ODIM + o]);
    out[BDIM * ODIM + b * ODIM + o] = cw;         // chosen_w = output 1

    // ---- ind_x: score = fl(fl(x+rel) - fl(x*rel)) ----
    {
        float x0 = xrow[0];
        float r0 = relx[o];
        best = __fsub_rn(__fadd_rn(x0, r0), __fmul_rn(x0, r0));
        idx = 0;
        int i = 1;
        for (; i + 4 <= IDIM; i += 4) {
            float a0 = xrow[i+0], r0_ = relx[(i+0) * ODIM + o];
            float a1 = xrow[i+1], r1_ = relx[(i+1) * ODIM + o];
            float a2 = xrow[i+2], r2_ = relx[(i+2) * ODIM + o];
            float a3 = xrow[i+3], r3_ = relx[(i+3) * ODIM + o];
            float s0 = __fsub_rn(__fadd_rn(a0, r0_), __fmul_rn(a0, r0_));
            float s1 = __fsub_rn(__fadd_rn(a1, r1_), __fmul_rn(a1, r1_));
            float s2 = __fsub_rn(__fadd_rn(a2, r2_), __fmul_rn(a2, r2_));
            float s3 = __fsub_rn(__fadd_rn(a3, r3_), __fmul_rn(a3, r3_));
            if (np_argmin_better(s0, best)) { best = s0; idx = i + 0; }
            if (np_argmin_better(s1, best)) { best = s1; idx = i + 1; }
            if (np_argmin_better(s2, best)) { best = s2; idx = i + 2; }
            if (np_argmin_better(s3, best)) { best = s3; idx = i + 3; }
        }
        for (; i < IDIM; ++i) {
            float a = xrow[i];
            float r = relx[i * ODIM + o];
            float s = __fsub_rn(__fadd_rn(a, r), __fmul_rn(a, r));
            if (np_argmin_better(s, best)) { best = s; idx = i; }
        }
    }
    float cx = fmaxf(xrow[idx], w[idx * ODIM + o]);
    out[b * ODIM + o] = cx;                       // chosen_x = output 0
}

extern "C" void kernel_launch(void* const* d_in, const int* in_sizes, int n_in,
                              void* d_out, int out_size, void* d_ws, size_t ws_size,
                              hipStream_t stream) {
    const float* x = (const float*)d_in[0];  // (B, I)
    const float* w = (const float*)d_in[1];  // (I, O)
    const float* t = (const float*)d_in[2];  // (B, O)
    float* out = (float*)d_out;              // [chosen_x | chosen_w]

    char* ws = (char*)d_ws;
    double* rx   = (double*)(ws);                                // 1 MB
    double* rw   = (double*)(ws + (1u << 20));                   // 1 MB
    float*  relx = (float*)(ws + (2u << 20));                    // 512 KB
    float*  relw = (float*)(ws + (2u << 20) + (512u << 10));     // 1 MB

    hipLaunchKernelGGL(recip_kernel, dim3(1024), dim3(256), 0, stream, x, w, rx, rw);
    hipLaunchKernelGGL(relx_kernel,  dim3(IDIM), dim3(ODIM), 0, stream, x, t, rx, relx);
    hipLaunchKernelGGL(relw_kernel,  dim3(ODIM), dim3(BDIM), 0, stream, w, t, rw, relw);
    hipLaunchKernelGGL(out_kernel,   dim3(BDIM), dim3(ODIM), 0, stream, x, w, relx, relw, out);
}

// Round 5
// 232.214 us; speedup vs baseline: 1.1427x; 1.1427x over previous
//
#include <hip/hip_runtime.h>
#include <math.h>

#define BDIM 512
#define IDIM 256
#define ODIM 512

// jnp.minimum(q, 1.0): NaN-propagating min with 1.0
__device__ __forceinline__ float np_min1(float q) {
    return (q < 1.0f) ? q : ((q != q) ? q : 1.0f);
}

// np.argmin update rule: strict < (first occurrence wins), NaN-first.
__device__ __forceinline__ bool np_argmin_better(float s, float best) {
    return (s < best) || (isnan(s) && !isnan(best));
}

// Correctly-rounded fp32 divide num/den given a correctly-rounded fp64
// reciprocal r = 1/(double)den, WITHOUT v_div_* (no VCC serialization).
// For this problem's dyadic inputs (uniform grid k*2^-23) quotients never
// hit fp32 rounding midpoints, so the <=2^-52-rel-error fp64 result
// converts to exactly the RN fp32 quotient. den==0 -> IEEE num/0 semantics.
__device__ __forceinline__ float div_rn_via_r64(float num, float den, double r) {
    double n   = (double)num;
    double q0  = n * r;
    double rem = fma(-(double)den, q0, n);
    double q   = fma(rem, r, q0);
    float  qf  = (float)q;
    return (den == 0.0f) ? num * (float)INFINITY : qf;
}

// K1: fp64 reciprocals of den = fl(1 - fl(1 - v)) for x and w.
__global__ __launch_bounds__(256) void recip_kernel(const float* __restrict__ x,
                                                    const float* __restrict__ w,
                                                    double* __restrict__ rx,
                                                    double* __restrict__ rw) {
    int idx = blockIdx.x * blockDim.x + threadIdx.x;
    const int n = BDIM * IDIM;  // 131072 (== IDIM*ODIM)
    const float* src = (idx < n) ? x : w;
    double*      dst = (idx < n) ? rx : rw;
    int j = (idx < n) ? idx : idx - n;
    float v   = src[j];
    float c   = __fsub_rn(1.0f, v);      // comp
    float den = __fsub_rn(1.0f, c);
    dst[j] = (den == 0.0f) ? (double)INFINITY : 1.0 / (double)den;
}

// K2: rel_x[i,o] = 1 - S/D, sequential-in-b (numpy order).
// Block = i (256 blocks -> grid-limited 2 waves/SIMD): x, rx wave-uniform
// (s_load); t coalesced. launch_bounds(.,2) allows 256 VGPR -> real ILP.
// Load-phase / compute-phase / add-phase split: one latency hit per batch.
__global__ __launch_bounds__(512, 2) void relx_kernel(const float* __restrict__ x,
                                                      const float* __restrict__ t,
                                                      const double* __restrict__ rx,
                                                      float* __restrict__ relx) {
    int o = threadIdx.x;   // 0..511
    int i = blockIdx.x;    // 0..255
    float S = 0.0f, D = 0.0f;
    for (int b = 0; b < BDIM; b += 16) {
        float tv[16]; float xv[16]; double r[16];
        #pragma unroll
        for (int u = 0; u < 16; ++u) tv[u] = t[(b + u) * ODIM + o];   // 16 vloads
        #pragma unroll
        for (int u = 0; u < 16; ++u) {
            xv[u] = x[(b + u) * IDIM + i];    // uniform -> s_load
            r[u]  = rx[(b + u) * IDIM + i];   // uniform -> s_load x2
        }
        float qm[16], xcs[16];
        #pragma unroll
        for (int u = 0; u < 16; ++u) {        // pure VALU, 16 indep chains
            float xc  = __fsub_rn(1.0f, xv[u]);   // x_comp
            float den = __fsub_rn(1.0f, xc);      // NOT simply xv (rounding!)
            float tc  = __fsub_rn(1.0f, tv[u]);   // t_comp
            float num = __fsub_rn(tc, xc);
            qm[u]  = np_min1(div_rn_via_r64(num, den, r[u]));
            xcs[u] = xc;
        }
        #pragma unroll
        for (int u = 0; u < 16; ++u) {        // exact sequential order
            S = __fadd_rn(S, qm[u]);
            D = __fadd_rn(D, xcs[u]);
        }
    }
    relx[i * ODIM + o] = __fsub_rn(1.0f, __fdiv_rn(S, D));  // one div/thread
}

// K3: rel_w[b,o] = 1 - S/D, sequential-in-i.
// Block = o (512 blocks -> 2 blocks/CU, 4 waves/SIMD): w, rw uniform s_load.
__global__ __launch_bounds__(512, 4) void relw_kernel(const float* __restrict__ w,
                                                      const float* __restrict__ t,
                                                      const double* __restrict__ rw,
                                                      float* __restrict__ relw) {
    int b = threadIdx.x;   // 0..511
    int o = blockIdx.x;    // 0..511
    float tc = __fsub_rn(1.0f, t[b * ODIM + o]);  // strided column, one-time
    float S = 0.0f, D = 0.0f;
    for (int i = 0; i < IDIM; i += 16) {
        float wv[16]; double r[16];
        #pragma unroll
        for (int u = 0; u < 16; ++u) {
            wv[u] = w[(i + u) * ODIM + o];    // uniform -> s_load
            r[u]  = rw[(i + u) * ODIM + o];   // uniform -> s_load x2
        }
        float qm[16], wcs[16];
        #pragma unroll
        for (int u = 0; u < 16; ++u) {
            float wc  = __fsub_rn(1.0f, wv[u]);   // w_comp
            float den = __fsub_rn(1.0f, wc);
            float num = __fsub_rn(tc, wc);
            qm[u]  = np_min1(div_rn_via_r64(num, den, r[u]));
            wcs[u] = wc;
        }
        #pragma unroll
        for (int u = 0; u < 16; ++u) {        // exact sequential order
            S = __fadd_rn(S, qm[u]);
            D = __fadd_rn(D, wcs[u]);
        }
    }
    relw[b * ODIM + o] = __fsub_rn(1.0f, __fdiv_rn(S, D));
}

// K4: both argmins + gathers, fp32 numpy-exact scores. Block = b, thread = o.
// +INF init with idx=0 is provably identical to seeding with s_0 under the
// NaN-first rule (s0<INF picks it unless s0 is NaN/INF; NaN branch picks it;
// s0==+INF keeps idx=0 == numpy first-occurrence).
__global__ __launch_bounds__(512, 4) void out_kernel(const float* __restrict__ x,
                                                     const float* __restrict__ w,
                                                     const float* __restrict__ relx,
                                                     const float* __restrict__ relw,
                                                     float* __restrict__ out) {
    __shared__ float xrow[IDIM];
    int o = threadIdx.x;   // 0..511
    int b = blockIdx.x;    // 0..511
    if (o < IDIM) xrow[o] = x[b * IDIM + o];
    __syncthreads();

    // ---- ind_w: score = fl(fl(w+rw) - fl(w*rw)) ----
    float rw = relw[b * ODIM + o];                // coalesced row read
    float best = (float)INFINITY; int idx = 0;
    for (int i = 0; i < IDIM; i += 8) {
        float a[8], s[8];
        #pragma unroll
        for (int u = 0; u < 8; ++u) a[u] = w[(i + u) * ODIM + o];  // coalesced
        #pragma unroll
        for (int u = 0; u < 8; ++u)
            s[u] = __fsub_rn(__fadd_rn(a[u], rw), __fmul_rn(a[u], rw));
        #pragma unroll
        for (int u = 0; u < 8; ++u)           // exact sequential scan
            if (np_argmin_better(s[u], best)) { best = s[u]; idx = i + u; }
    }
    float cw = fmaxf(xrow[idx], w[idx * ODIM + o]);
    out[BDIM * ODIM + b * ODIM + o] = cw;         // chosen_w = output 1

    // ---- ind_x: score = fl(fl(x+rel) - fl(x*rel)) ----
    best = (float)INFINITY; idx = 0;
    for (int i = 0; i < IDIM; i += 8) {
        float a[8], rl[8], s[8];
        #pragma unroll
        for (int u = 0; u < 8; ++u) {
            a[u]  = xrow[i + u];                   // LDS broadcast
            rl[u] = relx[(i + u) * ODIM + o];      // coalesced
        }
        #pragma unroll
        for (int u = 0; u < 8; ++u)
            s[u] = __fsub_rn(__fadd_rn(a[u], rl[u]), __fmul_rn(a[u], rl[u]));
        #pragma unroll
        for (int u = 0; u < 8; ++u)
            if (np_argmin_better(s[u], best)) { best = s[u]; idx = i + u; }
    }
    float cx = fmaxf(xrow[idx], w[idx * ODIM + o]);
    out[b * ODIM + o] = cx;                       // chosen_x = output 0
}

extern "C" void kernel_launch(void* const* d_in, const int* in_sizes, int n_in,
                              void* d_out, int out_size, void* d_ws, size_t ws_size,
                              hipStream_t stream) {
    const float* x = (const float*)d_in[0];  // (B, I)
    const float* w = (const float*)d_in[1];  // (I, O)
    const float* t = (const float*)d_in[2];  // (B, O)
    float* out = (float*)d_out;              // [chosen_x | chosen_w]

    char* ws = (char*)d_ws;
    double* rx   = (double*)(ws);                                // 1 MB
    double* rw   = (double*)(ws + (1u << 20));                   // 1 MB
    float*  relx = (float*)(ws + (2u << 20));                    // 512 KB
    float*  relw = (float*)(ws + (2u << 20) + (512u << 10));     // 1 MB

    hipLaunchKernelGGL(recip_kernel, dim3(1024), dim3(256), 0, stream, x, w, rx, rw);
    hipLaunchKernelGGL(relx_kernel,  dim3(IDIM), dim3(ODIM), 0, stream, x, t, rx, relx);
    hipLaunchKernelGGL(relw_kernel,  dim3(ODIM), dim3(BDIM), 0, stream, w, t, rw, relw);
    hipLaunchKernelGGL(out_kernel,   dim3(BDIM), dim3(ODIM), 0, stream, x, w, relx, relw, out);
}

// Round 6
// 151.343 us; speedup vs baseline: 1.7534x; 1.5343x over previous
//
#include <hip/hip_runtime.h>
#include <math.h>

#define BDIM 512
#define IDIM 256
#define ODIM 512

// jnp.minimum(q, 1.0): NaN-propagating min with 1.0
__device__ __forceinline__ float np_min1(float q) {
    return (q < 1.0f) ? q : ((q != q) ? q : 1.0f);
}

// np.argmin update rule: strict < (first occurrence wins), NaN-first.
__device__ __forceinline__ bool np_argmin_better(float s, float best) {
    return (s < best) || (isnan(s) && !isnan(best));
}

// Correctly-rounded fp32 divide num/den given correctly-rounded fp64
// reciprocal r = 1/(double)den. fp64 Markstein -> <=2^-52 rel error ->
// fp32 conversion is exactly the RN quotient (verified bit-stable since R2:
// absmax pinned at 0.00390625). den==0 -> IEEE num/0.
__device__ __forceinline__ float div_rn_via_r64(float num, float den, double r) {
    double n   = (double)num;
    double q0  = n * r;
    double rem = fma(-(double)den, q0, n);
    double q   = fma(rem, r, q0);
    float  qf  = (float)q;
    return (den == 0.0f) ? num * (float)INFINITY : qf;
}

// async global->LDS copy, 16B per lane. LDS dest = wave-uniform base + lane*16.
typedef const __attribute__((address_space(1))) unsigned int* gu32p;
typedef __attribute__((address_space(3))) unsigned int* lu32p;
__device__ __forceinline__ void async_cp16(const float* g, float* l) {
    __builtin_amdgcn_global_load_lds((gu32p)(const void*)g, (lu32p)(void*)l, 16, 0, 0);
}

// K1: fp64 reciprocals of den = fl(1 - fl(1 - v)) for x and w.
__global__ __launch_bounds__(256) void recip_kernel(const float* __restrict__ x,
                                                    const float* __restrict__ w,
                                                    double* __restrict__ rx,
                                                    double* __restrict__ rw) {
    int idx = blockIdx.x * blockDim.x + threadIdx.x;
    const int n = BDIM * IDIM;  // 131072 (== IDIM*ODIM)
    const float* src = (idx < n) ? x : w;
    double*      dst = (idx < n) ? rx : rw;
    int j = (idx < n) ? idx : idx - n;
    float v   = src[j];
    float c   = __fsub_rn(1.0f, v);      // comp
    float den = __fsub_rn(1.0f, c);
    dst[j] = (den == 0.0f) ? (double)INFINITY : 1.0 / (double)den;
}

// K2: rel_x[i,o] = 1 - S/D, sequential-in-b (numpy order).
// Block = i (256 -> 1 block/CU). x/rx columns in LDS once; t double-buffered
// 16-row chunks via global_load_lds + counted vmcnt + raw s_barrier (T3/T4).
#define XCH 16
__global__ __launch_bounds__(512) void relx_kernel(const float* __restrict__ x,
                                                   const float* __restrict__ t,
                                                   const double* __restrict__ rx,
                                                   float* __restrict__ relx) {
    __shared__ float  tbuf[2][XCH * ODIM];   // 2 x 32 KB
    __shared__ float  xcol[BDIM];            // 2 KB
    __shared__ double rxcol[BDIM];           // 4 KB  -> 70 KB total
    const int o = threadIdx.x;               // 0..511
    const int i = blockIdx.x;                // 0..255
    const int lane = o & 63, wv = o >> 6;

    // one-time column staging (uncoalesced gather, once)
    xcol[o]  = x[(size_t)o * IDIM + i];
    rxcol[o] = rx[(size_t)o * IDIM + i];

    // stage chunk 0 of t: per wave 1024 floats = 4 x 16B-per-lane instrs
    {
        const float* g = t + (size_t)wv * 1024 + (size_t)lane * 4;
        float* l = &tbuf[0][wv * 1024];
        #pragma unroll
        for (int r = 0; r < 4; ++r) async_cp16(g + r * 256, l + r * 256);
    }

    float S = 0.0f, D = 0.0f;
    for (int c = 0; c < BDIM / XCH; ++c) {   // 32 chunks
        if (c + 1 < BDIM / XCH) {
            const float* g = t + (size_t)(c + 1) * XCH * ODIM + (size_t)wv * 1024 + (size_t)lane * 4;
            float* l = &tbuf[(c + 1) & 1][wv * 1024];
            #pragma unroll
            for (int r = 0; r < 4; ++r) async_cp16(g + r * 256, l + r * 256);
            // drain chunk c's 4 loads, keep chunk c+1's 4 in flight
            if (c == 0) asm volatile("s_waitcnt vmcnt(4) lgkmcnt(0)" ::: "memory");
            else        asm volatile("s_waitcnt vmcnt(4)" ::: "memory");
        } else {
            asm volatile("s_waitcnt vmcnt(0)" ::: "memory");
        }
        __builtin_amdgcn_s_barrier();        // all waves' chunk-c loads done
        asm volatile("" ::: "memory");
        const float* tb = tbuf[c & 1];
        #pragma unroll 8
        for (int u = 0; u < XCH; ++u) {
            float  tv = tb[u * ODIM + o];    // 2-way bank (free)
            float  xv = xcol[c * XCH + u];   // uniform broadcast
            double r  = rxcol[c * XCH + u];  // uniform broadcast b64
            float xc  = __fsub_rn(1.0f, xv);     // x_comp
            float den = __fsub_rn(1.0f, xc);     // NOT simply xv (rounding!)
            float tc  = __fsub_rn(1.0f, tv);     // t_comp
            float num = __fsub_rn(tc, xc);
            float q   = np_min1(div_rn_via_r64(num, den, r));
            S = __fadd_rn(S, q);                 // exact sequential order
            D = __fadd_rn(D, xc);
        }
        asm volatile("" ::: "memory");
        __builtin_amdgcn_s_barrier();        // protect buf before overwrite
    }
    relx[(size_t)i * ODIM + o] = __fsub_rn(1.0f, __fdiv_rn(S, D));
}

// K3: rel_w[b,o] = 1 - S/D, sequential-in-i. Block = o (512), thread = b.
// w/rw columns fully staged in LDS up-front -> pure LDS/VALU loop.
__global__ __launch_bounds__(512) void relw_kernel(const float* __restrict__ w,
                                                   const float* __restrict__ t,
                                                   const double* __restrict__ rw,
                                                   float* __restrict__ relw) {
    __shared__ float  wcol[IDIM];            // 1 KB
    __shared__ double rwcol[IDIM];           // 2 KB
    const int b = threadIdx.x;               // 0..511
    const int o = blockIdx.x;                // 0..511
    if (b < IDIM) {
        wcol[b]  = w[(size_t)b * ODIM + o];
        rwcol[b] = rw[(size_t)b * ODIM + o];
    }
    float tc = __fsub_rn(1.0f, t[(size_t)b * ODIM + o]);
    __syncthreads();
    float S = 0.0f, D = 0.0f;
    #pragma unroll 8
    for (int i = 0; i < IDIM; ++i) {
        float  wvv = wcol[i];                // uniform broadcast
        double r   = rwcol[i];               // uniform broadcast
        float wc  = __fsub_rn(1.0f, wvv);    // w_comp
        float den = __fsub_rn(1.0f, wc);
        float num = __fsub_rn(tc, wc);
        float q   = np_min1(div_rn_via_r64(num, den, r));
        S = __fadd_rn(S, q);                 // exact sequential order
        D = __fadd_rn(D, wc);
    }
    relw[(size_t)b * ODIM + o] = __fsub_rn(1.0f, __fdiv_rn(S, D));
}

// K4: both argmin scans merged into one i-pass; w+relx rows double-buffered
// in LDS (8-row chunks, 65 KB -> 2 blocks/CU). Block = b, thread = o.
#define OCH 8
__global__ __launch_bounds__(512) void out_kernel(const float* __restrict__ x,
                                                  const float* __restrict__ w,
                                                  const float* __restrict__ relx,
                                                  const float* __restrict__ relw,
                                                  float* __restrict__ out) {
    __shared__ float wbuf[2][OCH * ODIM];    // 2 x 16 KB
    __shared__ float rbuf[2][OCH * ODIM];    // 2 x 16 KB
    __shared__ float xrow[IDIM];             // 1 KB
    const int o = threadIdx.x;               // 0..511
    const int b = blockIdx.x;                // 0..511
    const int lane = o & 63, wv = o >> 6;
    if (o < IDIM) xrow[o] = x[(size_t)b * IDIM + o];
    float rw = relw[(size_t)b * ODIM + o];   // coalesced; retired by vmcnt(4)

    {   // stage chunk 0: w rows 0..7 + relx rows 0..7; per wave 2+2 instrs
        const float* gw = w    + (size_t)wv * 512 + (size_t)lane * 4;
        const float* gr = relx + (size_t)wv * 512 + (size_t)lane * 4;
        float* lw = &wbuf[0][wv * 512];
        float* lr = &rbuf[0][wv * 512];
        #pragma unroll
        for (int r = 0; r < 2; ++r) {
            async_cp16(gw + r * 256, lw + r * 256);
            async_cp16(gr + r * 256, lr + r * 256);
        }
    }

    float bw = (float)INFINITY, bx = (float)INFINITY;  // +INF seed == first-occurrence
    int iw = 0, ix = 0;
    for (int c = 0; c < IDIM / OCH; ++c) {   // 32 chunks
        if (c + 1 < IDIM / OCH) {
            const float* gw = w    + (size_t)(c + 1) * OCH * ODIM + (size_t)wv * 512 + (size_t)lane * 4;
            const float* gr = relx + (size_t)(c + 1) * OCH * ODIM + (size_t)wv * 512 + (size_t)lane * 4;
            float* lw = &wbuf[(c + 1) & 1][wv * 512];
            float* lr = &rbuf[(c + 1) & 1][wv * 512];
            #pragma unroll
            for (int r = 0; r < 2; ++r) {
                async_cp16(gw + r * 256, lw + r * 256);
                async_cp16(gr + r * 256, lr + r * 256);
            }
            if (c == 0) asm volatile("s_waitcnt vmcnt(4) lgkmcnt(0)" ::: "memory");
            else        asm volatile("s_waitcnt vmcnt(4)" ::: "memory");
        } else {
            asm volatile("s_waitcnt vmcnt(0)" ::: "memory");
        }
        __builtin_amdgcn_s_barrier();
        asm volatile("" ::: "memory");
        const float* wb = wbuf[c & 1];
        const float* rb = rbuf[c & 1];
        #pragma unroll
        for (int u = 0; u < OCH; ++u) {
            int ii = c * OCH + u;
            float a  = wb[u * ODIM + o];     // 2-way bank (free)
            float rl = rb[u * ODIM + o];
            float xv = xrow[ii];             // uniform broadcast
            float sw = __fsub_rn(__fadd_rn(a, rw), __fmul_rn(a, rw));
            float sx = __fsub_rn(__fadd_rn(xv, rl), __fmul_rn(xv, rl));
            if (np_argmin_better(sw, bw)) { bw = sw; iw = ii; }  // sequential
            if (np_argmin_better(sx, bx)) { bx = sx; ix = ii; }
        }
        asm volatile("" ::: "memory");
        __builtin_amdgcn_s_barrier();
    }
    float cw = fmaxf(xrow[iw], w[(size_t)iw * ODIM + o]);
    float cx = fmaxf(xrow[ix], w[(size_t)ix * ODIM + o]);
    out[(size_t)BDIM * ODIM + (size_t)b * ODIM + o] = cw;  // chosen_w = out 1
    out[(size_t)b * ODIM + o] = cx;                        // chosen_x = out 0
}

extern "C" void kernel_launch(void* const* d_in, const int* in_sizes, int n_in,
                              void* d_out, int out_size, void* d_ws, size_t ws_size,
                              hipStream_t stream) {
    const float* x = (const float*)d_in[0];  // (B, I)
    const float* w = (const float*)d_in[1];  // (I, O)
    const float* t = (const float*)d_in[2];  // (B, O)
    float* out = (float*)d_out;              // [chosen_x | chosen_w]

    char* ws = (char*)d_ws;
    double* rx   = (double*)(ws);                                // 1 MB
    double* rw   = (double*)(ws + (1u << 20));                   // 1 MB
    float*  relx = (float*)(ws + (2u << 20));                    // 512 KB
    float*  relw = (float*)(ws + (2u << 20) + (512u << 10));     // 1 MB

    hipLaunchKernelGGL(recip_kernel, dim3(1024), dim3(256), 0, stream, x, w, rx, rw);
    hipLaunchKernelGGL(relx_kernel,  dim3(IDIM), dim3(512), 0, stream, x, t, rx, relx);
    hipLaunchKernelGGL(relw_kernel,  dim3(ODIM), dim3(512), 0, stream, w, t, rw, relw);
    hipLaunchKernelGGL(out_kernel,   dim3(BDIM), dim3(512), 0, stream, x, w, relx, relw, out);
}

// Round 7
// 111.825 us; speedup vs baseline: 2.3730x; 1.3534x over previous
//
#include <hip/hip_runtime.h>
#include <math.h>

#define BDIM 512
#define IDIM 256
#define ODIM 512

// 16B table entry: correctly-rounded fp64 reciprocal of den + the comp value.
struct __align__(16) XT { double r; float c; float pad; };

// jnp.minimum(q, 1.0): NaN-propagating min with 1.0
__device__ __forceinline__ float np_min1(float q) {
    float m = fminf(q, 1.0f);          // v_min_f32 (minNum; NaN fixed below)
    return (q != q) ? q : m;
}

// np.argmin update: strict < (first occurrence wins), NaN-first & sticky.
__device__ __forceinline__ bool np_argmin_better(float s, float best) {
    return (s < best) || (isnan(s) && !isnan(best));
}

// Correctly-rounded fp32 divide num/den as RN32(num * r), r = RN64(1/den).
// Proof: rel err of (double)num*r <= 2^-51.9; no fp32/fp32 quotient is a
// 25-bit midpoint (m*2^s = M*k, M odd >= 2^24 > m impossible) -> exclusion
// >= 2^-49 >> err. den==0 -> r=+INF -> num*INF = IEEE num/0 (+-INF, 0->NaN).
__device__ __forceinline__ float q32(float num, double r) {
    return (float)((double)num * r);
}

// async global->LDS, 16B/lane; LDS dest = wave-uniform base + lane*16.
typedef const __attribute__((address_space(1))) unsigned int* gu32p;
typedef __attribute__((address_space(3))) unsigned int* lu32p;
__device__ __forceinline__ void async_cp16(const float* g, float* l) {
    __builtin_amdgcn_global_load_lds((gu32p)(const void*)g, (lu32p)(void*)l, 16, 0, 0);
}

// K1: rel_x[i, o-half] = 1 - S/D, sequential-in-b (numpy order).
// Grid 512 = (i, oh): 2 independent blocks/CU. x-table built in-LDS;
// t streamed via double-buffered global_load_lds + counted vmcnt (T3/T4).
#define XCH 16
__global__ __launch_bounds__(256) void relx_kernel(const float* __restrict__ x,
                                                   const float* __restrict__ t,
                                                   float* __restrict__ relx) {
    __shared__ float tbuf0[XCH * 256];       // 16 KB
    __shared__ float tbuf1[XCH * 256];       // 16 KB
    __shared__ XT    xtab[BDIM];             // 8 KB
    const int tid = threadIdx.x;             // o within half: 0..255
    const int i   = blockIdx.x >> 1;         // 0..255
    const int oh  = blockIdx.x & 1;
    const int obase = oh * 256;
    const int l = tid & 63, wv = tid >> 6;   // 4 waves

    // build x-table: one fp64 divide per (b,i), 2 per thread, no chains
    for (int b = tid; b < BDIM; b += 256) {
        float xv  = x[(size_t)b * IDIM + i]; // strided gather, once
        float xc  = __fsub_rn(1.0f, xv);     // x_comp
        float den = __fsub_rn(1.0f, xc);     // NOT simply xv (rounding!)
        XT e; e.r = 1.0 / (double)den; e.c = xc; e.pad = 0.0f;
        xtab[b] = e;                         // den==0 -> r=+INF (IEEE)
    }
    {   // stage chunk 0 of t: wave wv stages rows wv*4..wv*4+3
        const float* g = t + (size_t)(wv * 4) * ODIM + obase + l * 4;
        float* lp = tbuf0 + (wv * 4) * 256 + l * 4;
        #pragma unroll
        for (int rr = 0; rr < 4; ++rr) async_cp16(g + rr * ODIM, lp + rr * 256);
    }
    __syncthreads();                         // drains vm+lds, incl chunk 0

    float S = 0.0f, D = 0.0f;
    for (int c = 0; c < BDIM / XCH; ++c) {   // 32 chunks
        if (c + 1 < BDIM / XCH) {
            const float* g = t + ((size_t)(c + 1) * XCH + wv * 4) * ODIM + obase + l * 4;
            float* lp = (((c + 1) & 1) ? tbuf1 : tbuf0) + (wv * 4) * 256 + l * 4;
            #pragma unroll
            for (int rr = 0; rr < 4; ++rr) async_cp16(g + rr * ODIM, lp + rr * 256);
            asm volatile("s_waitcnt vmcnt(4)" ::: "memory");  // chunk c done
        } else {
            asm volatile("s_waitcnt vmcnt(0)" ::: "memory");
        }
        __builtin_amdgcn_s_barrier();
        asm volatile("" ::: "memory");
        const float* tb = (c & 1) ? tbuf1 : tbuf0;
        #pragma unroll
        for (int u = 0; u < XCH; ++u) {
            float tv = tb[u * 256 + tid];    // conflict-free
            XT e = xtab[c * XCH + u];        // uniform broadcast b128
            float tc  = __fsub_rn(1.0f, tv); // t_comp
            float num = __fsub_rn(tc, e.c);
            float q   = np_min1(q32(num, e.r));
            S = __fadd_rn(S, q);             // exact sequential order
            D = __fadd_rn(D, e.c);
        }
        asm volatile("" ::: "memory");
        __builtin_amdgcn_s_barrier();        // buf reusable
    }
    relx[(size_t)i * ODIM + obase + tid] = __fsub_rn(1.0f, __fdiv_rn(S, D));
}

// K2: rel_w[b,o] = 1 - S/D, sequential-in-i. Block = o (512 thr = b).
// w-table in LDS (256 divides); output TRANSPOSED so the store coalesces.
__global__ __launch_bounds__(512) void relw_kernel(const float* __restrict__ w,
                                                   const float* __restrict__ t,
                                                   float* __restrict__ relwT) {
    __shared__ XT wtab[IDIM];                // 4 KB
    const int b = threadIdx.x;               // 0..511
    const int o = blockIdx.x;                // 0..511
    if (b < IDIM) {
        float wvv = w[(size_t)b * ODIM + o]; // strided gather, once
        float wc  = __fsub_rn(1.0f, wvv);    // w_comp
        float den = __fsub_rn(1.0f, wc);
        XT e; e.r = 1.0 / (double)den; e.c = wc; e.pad = 0.0f;
        wtab[b] = e;
    }
    float tc = __fsub_rn(1.0f, t[(size_t)b * ODIM + o]);  // strided, once
    __syncthreads();
    float S = 0.0f, D = 0.0f;
    #pragma unroll 8
    for (int i = 0; i < IDIM; ++i) {
        XT e = wtab[i];                      // uniform broadcast b128
        float num = __fsub_rn(tc, e.c);
        float q   = np_min1(q32(num, e.r));
        S = __fadd_rn(S, q);                 // exact sequential order
        D = __fadd_rn(D, e.c);
    }
    relwT[(size_t)o * BDIM + b] = __fsub_rn(1.0f, __fdiv_rn(S, D));  // coalesced
}

// K3: both argmins + gathers. Grid 1024 = (b, oh), 256 thr, 33 KB LDS
// -> 4 blocks/CU, 16 waves/CU for stall overlap. w+relx streamed dbuf.
#define OCH 8
__global__ __launch_bounds__(256) void out_kernel(const float* __restrict__ x,
                                                  const float* __restrict__ w,
                                                  const float* __restrict__ relx,
                                                  const float* __restrict__ relwT,
                                                  float* __restrict__ out) {
    __shared__ float wbuf0[OCH * 256], wbuf1[OCH * 256];   // 16 KB
    __shared__ float rbuf0[OCH * 256], rbuf1[OCH * 256];   // 16 KB
    __shared__ float xrow[IDIM];                           // 1 KB
    const int tid = threadIdx.x;             // o within half
    const int b   = blockIdx.x >> 1;         // 0..511
    const int oh  = blockIdx.x & 1;
    const int obase = oh * 256;
    const int o = obase + tid;
    const int l = tid & 63, wv = tid >> 6;   // 4 waves

    if (tid < IDIM) xrow[tid] = x[(size_t)b * IDIM + tid];  // coalesced
    float rw = relwT[(size_t)o * BDIM + b];  // scattered, 1/thread, hidden

    {   // stage chunk 0: wave wv stages rows wv*2..wv*2+1 of w and relx
        const float* gw = w    + (size_t)(wv * 2) * ODIM + obase + l * 4;
        const float* gr = relx + (size_t)(wv * 2) * ODIM + obase + l * 4;
        float* lw = wbuf0 + (wv * 2) * 256 + l * 4;
        float* lr = rbuf0 + (wv * 2) * 256 + l * 4;
        #pragma unroll
        for (int rr = 0; rr < 2; ++rr) {
            async_cp16(gw + rr * ODIM, lw + rr * 256);
            async_cp16(gr + rr * ODIM, lr + rr * 256);
        }
    }
    __syncthreads();

    float bw = (float)INFINITY, bx = (float)INFINITY;  // +INF seed == first-occ
    int iw = 0, ix = 0;
    for (int c = 0; c < IDIM / OCH; ++c) {   // 32 chunks
        if (c + 1 < IDIM / OCH) {
            const float* gw = w    + ((size_t)(c + 1) * OCH + wv * 2) * ODIM + obase + l * 4;
            const float* gr = relx + ((size_t)(c + 1) * OCH + wv * 2) * ODIM + obase + l * 4;
            float* lw = (((c + 1) & 1) ? wbuf1 : wbuf0) + (wv * 2) * 256 + l * 4;
            float* lr = (((c + 1) & 1) ? rbuf1 : rbuf0) + (wv * 2) * 256 + l * 4;
            #pragma unroll
            for (int rr = 0; rr < 2; ++rr) {
                async_cp16(gw + rr * ODIM, lw + rr * 256);
                async_cp16(gr + rr * ODIM, lr + rr * 256);
            }
            asm volatile("s_waitcnt vmcnt(4)" ::: "memory");
        } else {
            asm volatile("s_waitcnt vmcnt(0)" ::: "memory");
        }
        __builtin_amdgcn_s_barrier();
        asm volatile("" ::: "memory");
        const float* wb = (c & 1) ? wbuf1 : wbuf0;
        const float* rb = (c & 1) ? rbuf1 : rbuf0;
        #pragma unroll
        for (int u = 0; u < OCH; ++u) {
            int ii = c * OCH + u;
            float a  = wb[u * 256 + tid];    // conflict-free
            float rl = rb[u * 256 + tid];
            float xv = xrow[ii];             // uniform broadcast
            float sw = __fsub_rn(__fadd_rn(a,  rw), __fmul_rn(a,  rw));
            float sx = __fsub_rn(__fadd_rn(xv, rl), __fmul_rn(xv, rl));
            if (np_argmin_better(sw, bw)) { bw = sw; iw = ii; }  // sequential
            if (np_argmin_better(sx, bx)) { bx = sx; ix = ii; }
        }
        asm volatile("" ::: "memory");
        __builtin_amdgcn_s_barrier();
    }
    float cw = fmaxf(xrow[iw], w[(size_t)iw * ODIM + o]);
    float cx = fmaxf(xrow[ix], w[(size_t)ix * ODIM + o]);
    out[(size_t)BDIM * ODIM + (size_t)b * ODIM + o] = cw;  // chosen_w = out 1
    out[(size_t)b * ODIM + o] = cx;                        // chosen_x = out 0
}

extern "C" void kernel_launch(void* const* d_in, const int* in_sizes, int n_in,
                              void* d_out, int out_size, void* d_ws, size_t ws_size,
                              hipStream_t stream) {
    const float* x = (const float*)d_in[0];  // (B, I)
    const float* w = (const float*)d_in[1];  // (I, O)
    const float* t = (const float*)d_in[2];  // (B, O)
    float* out = (float*)d_out;              // [chosen_x | chosen_w]

    char* ws = (char*)d_ws;
    float* relx  = (float*)(ws);                         // I*O*4 = 512 KB
    float* relwT = (float*)(ws + (IDIM * ODIM * 4));     // O*B*4 = 1 MB

    hipLaunchKernelGGL(relx_kernel, dim3(2 * IDIM), dim3(256), 0, stream, x, t, relx);
    hipLaunchKernelGGL(relw_kernel, dim3(ODIM),     dim3(512), 0, stream, w, t, relwT);
    hipLaunchKernelGGL(out_kernel,  dim3(2 * BDIM), dim3(256), 0, stream, x, w, relx, relwT, out);
}